// Round 3
// baseline (1642.349 us; speedup 1.0000x reference)
//
#include <hip/hip_runtime.h>
#include <math.h>

// Problem constants (from reference): N_EDGES=500000, N_RELS=256, D=256.
#define D 256
#define R 256

__device__ __forceinline__ float sigmoidf(float x) {
    return 1.0f / (1.0f + expf(-x));
}

// ---- kernel 1: zero workspace (harness poisons ws with 0xAA every call) ----
__global__ void zero_ws(float* ws, int n) {
    int i = blockIdx.x * blockDim.x + threadIdx.x;
    if (i < n) ws[i] = 0.0f;
}

// ---- kernel 2: relation histogram (counts as float, integer-exact) ----
__global__ __launch_bounds__(256) void hist_kernel(const int* __restrict__ rel,
                                                   int E,
                                                   float* __restrict__ counts) {
    __shared__ int h[R];
    h[threadIdx.x] = 0;
    __syncthreads();
    for (int e = blockIdx.x * blockDim.x + threadIdx.x; e < E;
         e += gridDim.x * blockDim.x)
        atomicAdd(&h[rel[e]], 1);
    __syncthreads();
    atomicAdd(&counts[threadIdx.x], (float)h[threadIdx.x]);
}

// ---- kernel 3: gather + LDS-privatized segment sum ----
// grid: (edge_chunks, 4 dim-chunks of 64, 2 for src/dst). 64KB LDS -> 2 blk/CU.
__global__ __launch_bounds__(256) void scatter_kernel(
    const int* __restrict__ src_nid, const int* __restrict__ dst_nid,
    const int* __restrict__ rel, const float* __restrict__ emb,
    float* __restrict__ src_sum, float* __restrict__ dst_sum, int E, int epb) {
    __shared__ float acc[R * 64];  // 64 KB
    const int tid = threadIdx.x;
    for (int i = tid; i < R * 64; i += 256) acc[i] = 0.0f;
    __syncthreads();

    const int* nids = blockIdx.z ? dst_nid : src_nid;
    float* gsum     = blockIdx.z ? dst_sum : src_sum;
    const int dimbase = blockIdx.y * 64;
    const int lane = tid & 63;
    const int wave = tid >> 6;
    const int start = blockIdx.x * epb;
    const int end   = (start + epb < E) ? (start + epb) : E;

    for (int base = start + wave * 64; base < end; base += 256) {
        int rem = end - base;
        int cnt = rem < 64 ? rem : 64;
        int mynid = 0, myrel = 0;
        if (lane < cnt) {
            mynid = nids[base + lane];
            myrel = rel[base + lane];
        }
        int i = 0;
        for (; i + 8 <= cnt; i += 8) {
            int n[8], rr[8];
            float v[8];
#pragma unroll
            for (int j = 0; j < 8; j++) {
                n[j]  = __shfl(mynid, i + j);
                rr[j] = __shfl(myrel, i + j);
            }
#pragma unroll
            for (int j = 0; j < 8; j++)
                v[j] = emb[(size_t)n[j] * D + dimbase + lane];
#pragma unroll
            for (int j = 0; j < 8; j++)
                atomicAdd(&acc[rr[j] * 64 + lane], v[j]);
        }
        for (; i < cnt; i++) {
            int n0 = __shfl(mynid, i);
            int r0 = __shfl(myrel, i);
            float v0 = emb[(size_t)n0 * D + dimbase + lane];
            atomicAdd(&acc[r0 * 64 + lane], v0);
        }
    }
    __syncthreads();
    // flush: 16384 values, coalesced within 64-dim rows
    for (int i = 0; i < 64; i++) {
        int idx = tid + i * 256;
        int r  = idx >> 6;
        int dl = idx & 63;
        atomicAdd(&gsum[r * D + dimbase + dl], acc[idx]);
    }
}

// ---- kernel 4: means + GRU cell for src and dst, one block per relation ----
__global__ __launch_bounds__(256) void gru_kernel(
    const float* __restrict__ src_sum, const float* __restrict__ dst_sum,
    const float* __restrict__ counts, const float* __restrict__ dyn,
    const float* __restrict__ W_ih, const float* __restrict__ W_hh,
    const float* __restrict__ b_ih, const float* __restrict__ b_hh,
    float* __restrict__ out) {
    __shared__ float xs[D], xd[D], hs[D], hd[D];
    const int r = blockIdx.x, t = threadIdx.x;
    float inv = 1.0f / fmaxf(counts[r], 1.0f);
    xs[t] = src_sum[r * D + t] * inv;
    xd[t] = dst_sum[r * D + t] * inv;
    float h_s = dyn[(r * D + t) * 2 + 0];
    float h_d = dyn[(r * D + t) * 2 + 1];
    hs[t] = h_s;
    hd[t] = h_d;
    __syncthreads();

    float gis[3], gid[3], ghs[3], ghd[3];
#pragma unroll
    for (int g = 0; g < 3; g++) {
        int row = g * D + t;
        const float4* wi = (const float4*)(W_ih + (size_t)row * D);
        const float4* wh = (const float4*)(W_hh + (size_t)row * D);
        float ais = 0.f, aid = 0.f, ahs = 0.f, ahd = 0.f;
        for (int k = 0; k < D / 4; k++) {
            float4 a = wi[k];
            float4 b = wh[k];
            int k4 = k * 4;
            ais += a.x * xs[k4] + a.y * xs[k4 + 1] + a.z * xs[k4 + 2] + a.w * xs[k4 + 3];
            aid += a.x * xd[k4] + a.y * xd[k4 + 1] + a.z * xd[k4 + 2] + a.w * xd[k4 + 3];
            ahs += b.x * hs[k4] + b.y * hs[k4 + 1] + b.z * hs[k4 + 2] + b.w * hs[k4 + 3];
            ahd += b.x * hd[k4] + b.y * hd[k4 + 1] + b.z * hd[k4 + 2] + b.w * hd[k4 + 3];
        }
        float bi = b_ih[row];
        float bh = b_hh[row];
        gis[g] = ais + bi; gid[g] = aid + bi;
        ghs[g] = ahs + bh; ghd[g] = ahd + bh;
    }
    float rs = sigmoidf(gis[0] + ghs[0]);
    float zs = sigmoidf(gis[1] + ghs[1]);
    float ns = tanhf(gis[2] + rs * ghs[2]);
    float new_s = (1.0f - zs) * ns + zs * h_s;

    float rd = sigmoidf(gid[0] + ghd[0]);
    float zd = sigmoidf(gid[1] + ghd[1]);
    float nd = tanhf(gid[2] + rd * ghd[2]);
    float new_d = (1.0f - zd) * nd + zd * h_d;

    // Output is fp32 (reference output dtype float32): shape (R,1,D,2) flat.
    out[(r * D + t) * 2 + 0] = new_s;
    out[(r * D + t) * 2 + 1] = new_d;
}

extern "C" void kernel_launch(void* const* d_in, const int* in_sizes, int n_in,
                              void* d_out, int out_size, void* d_ws, size_t ws_size,
                              hipStream_t stream) {
    const int* src_nid = (const int*)d_in[0];
    const int* dst_nid = (const int*)d_in[1];
    const int* rel     = (const int*)d_in[2];
    const float* emb   = (const float*)d_in[3];
    const float* dyn   = (const float*)d_in[4];
    const float* W_ih  = (const float*)d_in[5];
    const float* W_hh  = (const float*)d_in[6];
    const float* b_ih  = (const float*)d_in[7];
    const float* b_hh  = (const float*)d_in[8];
    float* out = (float*)d_out;
    const int E = in_sizes[0];

    float* ws      = (float*)d_ws;
    float* src_sum = ws;               // R*D
    float* dst_sum = ws + R * D;       // R*D
    float* counts  = ws + 2 * R * D;   // R
    const int nzero = 2 * R * D + R;

    zero_ws<<<(nzero + 255) / 256, 256, 0, stream>>>(ws, nzero);
    hist_kernel<<<256, 256, 0, stream>>>(rel, E, counts);

    const int chunks = 64;                      // 64 x 4 x 2 = 512 blocks, 2/CU
    const int epb = (E + chunks - 1) / chunks;  // edges per block
    scatter_kernel<<<dim3(chunks, 4, 2), 256, 0, stream>>>(
        src_nid, dst_nid, rel, emb, src_sum, dst_sum, E, epb);

    gru_kernel<<<R, 256, 0, stream>>>(src_sum, dst_sum, counts, dyn, W_ih, W_hh,
                                      b_ih, b_hh, out);
}

// Round 4
// 1555.481 us; speedup vs baseline: 1.0558x; 1.0558x over previous
//
#include <hip/hip_runtime.h>
#include <math.h>

// Problem constants (from reference): N_EDGES=500000, N_RELS=256, D=256.
#define D 256
#define R 256
#define DIMC 64  // dims per y-block

__device__ __forceinline__ float sigmoidf(float x) {
    return 1.0f / (1.0f + expf(-x));
}

// ---- kernel 1: zero workspace (harness poisons ws with 0xAA every call) ----
__global__ void zero_ws(float* ws, int n) {
    int i = blockIdx.x * blockDim.x + threadIdx.x;
    if (i < n) ws[i] = 0.0f;
}

// ---- kernel 2: relation histogram (counts as float, integer-exact) ----
__global__ __launch_bounds__(256) void hist_kernel(const int* __restrict__ rel,
                                                   int E,
                                                   float* __restrict__ counts) {
    __shared__ int h[R];
    h[threadIdx.x] = 0;
    __syncthreads();
    for (int e = blockIdx.x * blockDim.x + threadIdx.x; e < E;
         e += gridDim.x * blockDim.x)
        atomicAdd(&h[rel[e]], 1);
    __syncthreads();
    atomicAdd(&counts[threadIdx.x], (float)h[threadIdx.x]);
}

// ---- kernel 3: gather + LDS-privatized segment sum ----
// 1024-thread blocks (16 waves) share one 64KB rel-private accumulator.
// __launch_bounds__(1024,8): 8 waves/SIMD -> <=64 VGPRs -> 2 blocks/CU
// -> 32 waves/CU, each wave keeps 16 gathers (256B each) in flight.
__global__ __launch_bounds__(1024, 8) void scatter_kernel(
    const int* __restrict__ src_nid, const int* __restrict__ dst_nid,
    const int* __restrict__ rel, const float* __restrict__ emb,
    float* __restrict__ src_sum, float* __restrict__ dst_sum, int E, int epb) {
    __shared__ float acc[R * DIMC];  // 64 KB
    const int tid = threadIdx.x;
    for (int i = tid; i < R * DIMC; i += 1024) acc[i] = 0.0f;
    __syncthreads();

    const int* nids = blockIdx.z ? dst_nid : src_nid;
    float* gsum     = blockIdx.z ? dst_sum : src_sum;
    const int dimbase = blockIdx.y * DIMC;
    const int lane = tid & 63;
    const int wave = tid >> 6;  // 0..15
    const int start = blockIdx.x * epb;
    const int end   = (start + epb < E) ? (start + epb) : E;
    const int dl = dimbase + lane;  // this lane's dim within the row

    for (int base = start + wave * 64; base < end; base += 1024) {
        int rem = end - base;
        int cnt = rem < 64 ? rem : 64;
        int mynid = 0, myrel = 0;
        if (lane < cnt) {
            mynid = nids[base + lane];
            myrel = rel[base + lane];
        }
        int i = 0;
        for (; i + 16 <= cnt; i += 16) {
            float v[16];
#pragma unroll
            for (int j = 0; j < 16; j++) {
                int n = __builtin_amdgcn_readlane(mynid, i + j);  // wave-uniform
                v[j] = emb[(size_t)n * D + dl];
            }
#pragma unroll
            for (int j = 0; j < 16; j++) {
                int rr = __builtin_amdgcn_readlane(myrel, i + j);
                atomicAdd(&acc[rr * DIMC + lane], v[j]);
            }
        }
        for (; i < cnt; i++) {
            int n  = __builtin_amdgcn_readlane(mynid, i);
            int rr = __builtin_amdgcn_readlane(myrel, i);
            float v = emb[(size_t)n * D + dl];
            atomicAdd(&acc[rr * DIMC + lane], v);
        }
    }
    __syncthreads();
    // flush: 16384 floats, coalesced in 64-dim rows
    for (int i = tid; i < R * DIMC; i += 1024) {
        int r = i >> 6;
        int d = i & 63;
        atomicAdd(&gsum[r * D + dimbase + d], acc[i]);
    }
}

// ---- kernel 4: means + GRU cell for src and dst, one block per relation ----
__global__ __launch_bounds__(256) void gru_kernel(
    const float* __restrict__ src_sum, const float* __restrict__ dst_sum,
    const float* __restrict__ counts, const float* __restrict__ dyn,
    const float* __restrict__ W_ih, const float* __restrict__ W_hh,
    const float* __restrict__ b_ih, const float* __restrict__ b_hh,
    float* __restrict__ out) {
    __shared__ float xs[D], xd[D], hs[D], hd[D];
    const int r = blockIdx.x, t = threadIdx.x;
    float inv = 1.0f / fmaxf(counts[r], 1.0f);
    xs[t] = src_sum[r * D + t] * inv;
    xd[t] = dst_sum[r * D + t] * inv;
    float h_s = dyn[(r * D + t) * 2 + 0];
    float h_d = dyn[(r * D + t) * 2 + 1];
    hs[t] = h_s;
    hd[t] = h_d;
    __syncthreads();

    float gis[3], gid[3], ghs[3], ghd[3];
#pragma unroll
    for (int g = 0; g < 3; g++) {
        int row = g * D + t;
        const float4* wi = (const float4*)(W_ih + (size_t)row * D);
        const float4* wh = (const float4*)(W_hh + (size_t)row * D);
        float ais = 0.f, aid = 0.f, ahs = 0.f, ahd = 0.f;
        for (int k = 0; k < D / 4; k++) {
            float4 a = wi[k];
            float4 b = wh[k];
            int k4 = k * 4;
            ais += a.x * xs[k4] + a.y * xs[k4 + 1] + a.z * xs[k4 + 2] + a.w * xs[k4 + 3];
            aid += a.x * xd[k4] + a.y * xd[k4 + 1] + a.z * xd[k4 + 2] + a.w * xd[k4 + 3];
            ahs += b.x * hs[k4] + b.y * hs[k4 + 1] + b.z * hs[k4 + 2] + b.w * hs[k4 + 3];
            ahd += b.x * hd[k4] + b.y * hd[k4 + 1] + b.z * hd[k4 + 2] + b.w * hd[k4 + 3];
        }
        float bi = b_ih[row];
        float bh = b_hh[row];
        gis[g] = ais + bi; gid[g] = aid + bi;
        ghs[g] = ahs + bh; ghd[g] = ahd + bh;
    }
    float rs = sigmoidf(gis[0] + ghs[0]);
    float zs = sigmoidf(gis[1] + ghs[1]);
    float ns = tanhf(gis[2] + rs * ghs[2]);
    float new_s = (1.0f - zs) * ns + zs * h_s;

    float rd = sigmoidf(gid[0] + ghd[0]);
    float zd = sigmoidf(gid[1] + ghd[1]);
    float nd = tanhf(gid[2] + rd * ghd[2]);
    float new_d = (1.0f - zd) * nd + zd * h_d;

    // Output is fp32 (reference output dtype float32): shape (R,1,D,2) flat.
    out[(r * D + t) * 2 + 0] = new_s;
    out[(r * D + t) * 2 + 1] = new_d;
}

extern "C" void kernel_launch(void* const* d_in, const int* in_sizes, int n_in,
                              void* d_out, int out_size, void* d_ws, size_t ws_size,
                              hipStream_t stream) {
    const int* src_nid = (const int*)d_in[0];
    const int* dst_nid = (const int*)d_in[1];
    const int* rel     = (const int*)d_in[2];
    const float* emb   = (const float*)d_in[3];
    const float* dyn   = (const float*)d_in[4];
    const float* W_ih  = (const float*)d_in[5];
    const float* W_hh  = (const float*)d_in[6];
    const float* b_ih  = (const float*)d_in[7];
    const float* b_hh  = (const float*)d_in[8];
    float* out = (float*)d_out;
    const int E = in_sizes[0];

    float* ws      = (float*)d_ws;
    float* src_sum = ws;               // R*D
    float* dst_sum = ws + R * D;       // R*D
    float* counts  = ws + 2 * R * D;   // R
    const int nzero = 2 * R * D + R;

    zero_ws<<<(nzero + 255) / 256, 256, 0, stream>>>(ws, nzero);
    hist_kernel<<<256, 256, 0, stream>>>(rel, E, counts);

    // 64 x 4 x 2 = 512 blocks of 1024 threads -> 2 blocks/CU, 32 waves/CU
    const int chunks = 64;
    const int epb = (E + chunks - 1) / chunks;  // edges per block
    scatter_kernel<<<dim3(chunks, 4, 2), 1024, 0, stream>>>(
        src_nid, dst_nid, rel, emb, src_sum, dst_sum, E, epb);

    gru_kernel<<<R, 256, 0, stream>>>(src_sum, dst_sum, counts, dyn, W_ih, W_hh,
                                      b_ih, b_hh, out);
}